// Round 1
// 622.202 us; speedup vs baseline: 1.3161x; 1.3161x over previous
//
#include <hip/hip_runtime.h>
#include <math.h>

// GraphSwinWindowContext: B=32, H=W=192, C=64, WS=6, SS=3, NH=NW=32. fp32 in/out.
//
// Output has only B*32*32*4 = 131072 distinct C-vectors (constant per
// (window, quadrant) 3x3 patch) -> per-pixel 64x64 linears collapse 9x.
//
// Round-4 changes vs round 3:
//  * Matvec broadcast: __shfl(m,k,64) lowered to ds_bpermute_b32 (DS op) even
//    for constant k -> 64 DS ops/row x 327680 rows = 2.1e7 wave DS ops.
//    Replaced with __builtin_amdgcn_readlane -> v_readlane+v_fmac, pure VALU,
//    zero DS traffic in the matvec.
//  * Accumulator split into 4 partials: serial fmac dep chain 64 -> 16 deep.
//  * LN reductions: sum(y) and sum(y^2) in ONE interleaved butterfly
//    (var = E[y^2] - m^2; var ~5e-3 >> m^2*ulp, cancellation-safe), halving
//    the serial reduction latency vs two dependent wsum64 passes.
//
// Pipeline:
//  A) k_blocksum: 3x3-pixel block sums S[B,64,64,C]           (reads 302MB)
//  B) k_token:    pooled(reg/shift) -> lin+LN+GELU -> tok     (65536 rows)
//  C) k_fuse:     tokreg+tokshift -> lin+LN+GELU -> h1        (131072 rows)
//  D) k_outbc:    h1 -> lin+LN+GELU -> broadcast 3x3 to out   (writes 302MB)
//
// ws layout:
//  [0, 33554432)        : S fp32 [B][64][64][C]   -- reused as h1 after k_token
//  [33554432, 50331648) : tok fp32 [2][B][32][32][C]

#define HH 192
#define WW 192
#define CC 64

__device__ __forceinline__ float gelu_exact(float x) {
    return 0.5f * x * (1.0f + erff(x * 0.70710678118654752440f));
}

// Broadcast lane k's value to all lanes: v_readlane_b32 (VALU, no DS).
__device__ __forceinline__ float bcast(float v, int k) {
    return __int_as_float(__builtin_amdgcn_readlane(__float_as_int(v), k));
}

// y[lane] = bias + sum_k m[k] * Wc[k]; m distributed one element per lane,
// Wc[k] = W[k][lane] resident in VGPRs. 4 partial sums break the fp chain.
__device__ __forceinline__ float matvec64(float m, const float* Wc, float bias) {
    float y0 = bias, y1 = 0.f, y2 = 0.f, y3 = 0.f;
#pragma unroll
    for (int k = 0; k < 64; k += 4) {
        y0 += bcast(m, k)     * Wc[k];
        y1 += bcast(m, k + 1) * Wc[k + 1];
        y2 += bcast(m, k + 2) * Wc[k + 2];
        y3 += bcast(m, k + 3) * Wc[k + 3];
    }
    return (y0 + y1) + (y2 + y3);
}

// LayerNorm over the 64 lanes + affine + exact GELU. One interleaved butterfly
// computes s1=sum(y), s2=sum(y^2); the two chains are independent and overlap.
__device__ __forceinline__ float ln_gelu(float y, float g, float b) {
    float s1 = y, s2 = y * y;
#pragma unroll
    for (int off = 32; off > 0; off >>= 1) {
        s1 += __shfl_xor(s1, off, 64);
        s2 += __shfl_xor(s2, off, 64);
    }
    float m = s1 * (1.0f / 64.0f);
    float v = s2 * (1.0f / 64.0f) - m * m;
    v = v < 0.f ? 0.f : v;
    return gelu_exact((y - m) * rsqrtf(v + 1e-5f) * g + b);
}

// ---------------- Kernel A: 3x3 pixel-block channel sums --------------------
// S[b][by][bx][c] = sum_{dy,dx<3} grid[b][3by+dy][3bx+dx][c], by,bx in [0,64)
extern "C" __global__ __launch_bounds__(256)
void k_blocksum(const float* __restrict__ h, float* __restrict__ S) {
    int bby = blockIdx.x;              // b*64 + by
    int b = bby >> 6, by = bby & 63;
    for (int item = threadIdx.x; item < 512; item += 256) {
        int bx = item >> 3;
        int c0 = (item & 7) * 8;
        float acc[8] = {0.f, 0.f, 0.f, 0.f, 0.f, 0.f, 0.f, 0.f};
#pragma unroll
        for (int dy = 0; dy < 3; ++dy) {
#pragma unroll
            for (int dx = 0; dx < 3; ++dx) {
                int y = by * 3 + dy, x = bx * 3 + dx;
                const float4* p = reinterpret_cast<const float4*>(
                    h + (((size_t)b * HH + y) * WW + x) * CC + c0);
                float4 v0 = p[0], v1 = p[1];
                acc[0] += v0.x; acc[1] += v0.y; acc[2] += v0.z; acc[3] += v0.w;
                acc[4] += v1.x; acc[5] += v1.y; acc[6] += v1.z; acc[7] += v1.w;
            }
        }
        float4* o = reinterpret_cast<float4*>(S + (((size_t)bby) * 64 + bx) * CC + c0);
        o[0] = make_float4(acc[0], acc[1], acc[2], acc[3]);
        o[1] = make_float4(acc[4], acc[5], acc[6], acc[7]);
    }
}

// ---------------- Kernel B: token projection (reg + shifted) ----------------
// rows: mode(2) x b(32) x wy(32) x wx(32) = 65536; one wave computes 16 rows.
extern "C" __global__ __launch_bounds__(256)
void k_token(const float* __restrict__ S,
             const float* __restrict__ Wt, const float* __restrict__ bt,
             const float* __restrict__ gt, const float* __restrict__ bet,
             float* __restrict__ tok) {
    int lane = threadIdx.x & 63;
    int wg = blockIdx.x * 4 + (threadIdx.x >> 6);
    float Wc[64];
#pragma unroll
    for (int k = 0; k < 64; ++k) Wc[k] = Wt[k * 64 + lane];
    float bias = bt[lane], gg = gt[lane], bb = bet[lane];
    int row0 = wg * 16;
    for (int i = 0; i < 16; ++i) {
        int row = row0 + i;
        int mode = row >> 15;
        int r = row & 32767;
        int b = r >> 10, wy = (r >> 5) & 31, wx = r & 31;
        int r0, r1, c0, c1;
        if (mode == 0) { r0 = 2 * wy;     r1 = 2 * wy + 1;        c0 = 2 * wx;     c1 = 2 * wx + 1; }
        else           { r0 = 2 * wy + 1; r1 = (2 * wy + 2) & 63; c0 = 2 * wx + 1; c1 = (2 * wx + 2) & 63; }
        const float* Sb = S + (size_t)b * 64 * 64 * 64;
        float pooled = (Sb[(r0 * 64 + c0) * 64 + lane] + Sb[(r0 * 64 + c1) * 64 + lane] +
                        Sb[(r1 * 64 + c0) * 64 + lane] + Sb[(r1 * 64 + c1) * 64 + lane]) * (1.0f / 36.0f);
        float y = matvec64(pooled, Wc, bias);
        tok[(size_t)row * 64 + lane] = ln_gelu(y, gg, bb);
    }
}

// ---------------- Kernel C: fuse block ---------------------------------------
// rows: b(32) x wy(32) x wx(32) x q(4) = 131072; one wave computes 16 rows.
extern "C" __global__ __launch_bounds__(256)
void k_fuse(const float* __restrict__ tok,
            const float* __restrict__ Wf, const float* __restrict__ bf_,
            const float* __restrict__ gf, const float* __restrict__ bef,
            float* __restrict__ h1) {
    int lane = threadIdx.x & 63;
    int wg = blockIdx.x * 4 + (threadIdx.x >> 6);
    float Wc[64];
#pragma unroll
    for (int k = 0; k < 64; ++k) Wc[k] = Wf[k * 64 + lane];
    float fb = bf_[lane], fg = gf[lane], fbe = bef[lane];
    int row0 = wg * 16;
    for (int i = 0; i < 16; ++i) {
        int row = row0 + i;
        int b = row >> 12;
        int rem = row & 4095;
        int wy = rem >> 7, wx = (rem >> 2) & 31, q = rem & 3;
        int sy = (wy + 31 + (q >> 1)) & 31;
        int sx = (wx + 31 + (q & 1)) & 31;
        const float* t0 = tok + (size_t)b * 65536;
        const float* t1 = tok + 2097152 + (size_t)b * 65536;
        float m = t0[(wy * 32 + wx) * 64 + lane] + t1[(sy * 32 + sx) * 64 + lane];
        float y = matvec64(m, Wc, fb);
        h1[(size_t)row * 64 + lane] = ln_gelu(y, fg, fbe);
    }
}

// ---------------- Kernel D: out block + 3x3 broadcast store ------------------
extern "C" __global__ __launch_bounds__(256)
void k_outbc(const float* __restrict__ h1,
             const float* __restrict__ Wo, const float* __restrict__ bo_,
             const float* __restrict__ go, const float* __restrict__ beo,
             float* __restrict__ out) {
    int lane = threadIdx.x & 63;
    int wg = blockIdx.x * 4 + (threadIdx.x >> 6);
    float Wc[64];
#pragma unroll
    for (int k = 0; k < 64; ++k) Wc[k] = Wo[k * 64 + lane];
    float ob = bo_[lane], og = go[lane], obe = beo[lane];
    int row0 = wg * 16;
    for (int i = 0; i < 16; ++i) {
        int row = row0 + i;
        float m = h1[(size_t)row * 64 + lane];
        float z = matvec64(m, Wc, ob);
        float o = ln_gelu(z, og, obe);
        // broadcast to the 3x3 pixel patch
        int b = row >> 12;
        int rem = row & 4095;
        int wy = rem >> 7, wx = (rem >> 2) & 31, q = rem & 3;
        int y0 = wy * 6 + (q >> 1) * 3;
        int x0 = wx * 6 + (q & 1) * 3;
        float* obase = out + (((size_t)b * HH + y0) * WW + x0) * CC + lane;
#pragma unroll
        for (int dy = 0; dy < 3; ++dy) {
#pragma unroll
            for (int dx = 0; dx < 3; ++dx) {
                obase[((size_t)dy * WW + dx) * CC] = o;
            }
        }
    }
}

extern "C" void kernel_launch(void* const* d_in, const int* in_sizes, int n_in,
                              void* d_out, int out_size, void* d_ws, size_t ws_size,
                              hipStream_t stream) {
    const float* h   = (const float*)d_in[0];
    const float* tW  = (const float*)d_in[1];
    const float* tb  = (const float*)d_in[2];
    const float* tg  = (const float*)d_in[3];
    const float* tbe = (const float*)d_in[4];
    const float* fW  = (const float*)d_in[5];
    const float* fb  = (const float*)d_in[6];
    const float* fg  = (const float*)d_in[7];
    const float* fbe = (const float*)d_in[8];
    const float* oW  = (const float*)d_in[9];
    const float* ob  = (const float*)d_in[10];
    const float* og  = (const float*)d_in[11];
    const float* obe = (const float*)d_in[12];
    float* out = (float*)d_out;

    char* ws = (char*)d_ws;
    float* S   = (float*)(ws);              // 33,554,432 B; reused as h1
    float* tok = (float*)(ws + 33554432);   // 16,777,216 B
    float* h1  = S;

    hipLaunchKernelGGL(k_blocksum, dim3(2048), dim3(256), 0, stream, h, S);
    hipLaunchKernelGGL(k_token, dim3(1024), dim3(256), 0, stream,
                       S, tW, tb, tg, tbe, tok);
    hipLaunchKernelGGL(k_fuse, dim3(2048), dim3(256), 0, stream,
                       tok, fW, fb, fg, fbe, h1);
    hipLaunchKernelGGL(k_outbc, dim3(2048), dim3(256), 0, stream,
                       h1, oW, ob, og, obe, out);
}